// Round 1
// baseline (742.553 us; speedup 1.0000x reference)
//
#include <hip/hip_runtime.h>
#include <math.h>

#define NBATCH 256
#define NNODE  512
#define NFP    68   // padded feature count; 0..63 = state dims, 64..65 = inputs, 66..67 pad
#define ND     64

// ---------------- adjacency preprocessing ----------------
__global__ void k_dinv(const float* __restrict__ adj, float* __restrict__ dinv) {
  int j = blockIdx.x;
  float s = 0.0f;
  for (int i = threadIdx.x; i < NNODE; i += 64) s += adj[j * NNODE + i];
  #pragma unroll
  for (int off = 32; off > 0; off >>= 1) s += __shfl_down(s, off);
  if (threadIdx.x == 0) dinv[j] = 1.0f / (1.0f + s);
}

// A[i][j] = (adj[j][i] + (i==j)) * dinv[j]   (random-walk transpose)
__global__ void k_buildA(const float* __restrict__ adj, const float* __restrict__ dinv,
                         float* __restrict__ A) {
  int i = blockIdx.x;
  for (int j = threadIdx.x; j < NNODE; j += blockDim.x) {
    float v = adj[j * NNODE + i] + ((i == j) ? 1.0f : 0.0f);
    A[i * NNODE + j] = v * dinv[j];
  }
}

// loader for X[b][m][f'] as float4 groups g (g<16: state-like cols, g==16: [in0,in1,0,0])
template<int SRC>
__device__ __forceinline__ float4 loadX4(const float* __restrict__ s64,
                                         const float* __restrict__ inp,
                                         const float* __restrict__ xbuf,
                                         int b, int m, int g) {
  if (SRC == 1) {
    return *reinterpret_cast<const float4*>(&xbuf[((size_t)b * NNODE + m) * NFP + g * 4]);
  } else {
    if (g < 16)
      return *reinterpret_cast<const float4*>(&s64[((size_t)b * NNODE + m) * ND + g * 4]);
    float4 r;
    r.x = inp[(size_t)b * NNODE * 2 + m * 2 + 0];
    r.y = inp[(size_t)b * NNODE * 2 + m * 2 + 1];
    r.z = 0.0f; r.w = 0.0f;
    return r;
  }
}

// Y[b][n][f'] = sum_m A[n][m] * X[b][m][f']   (optionally Y = 2*acc - X0 when EPI)
// block tile: 128 rows x 66 cols, one batch; 256 threads, per-thread 8x4 + 1 extra col
template<int SRC, int EPI>
__global__ __launch_bounds__(256) void k_diffstep(
    const float* __restrict__ A,
    const float* __restrict__ s64,
    const float* __restrict__ inp,
    const float* __restrict__ xbuf,
    const float* __restrict__ x0s64,
    float* __restrict__ Y) {
  __shared__ float AsT[32][136];   // transposed A tile: [m][row]
  __shared__ float Xs[32][NFP];
  const int b  = blockIdx.y;
  const int n0 = blockIdx.x * 128;
  const int tid = threadIdx.x;
  const int tr = tid >> 4;     // 0..15 -> rows tr*8..+7
  const int tc = tid & 15;     // cols tc*4..+3
  const int er = tid & 127;    // extra-col row
  const int ec = tid >> 7;     // extra col 64+ec
  float acc[8][4];
  #pragma unroll
  for (int i = 0; i < 8; ++i)
    #pragma unroll
    for (int j = 0; j < 4; ++j) acc[i][j] = 0.0f;
  float acce = 0.0f;

  for (int m0 = 0; m0 < NNODE; m0 += 32) {
    #pragma unroll
    for (int it = 0; it < 4; ++it) {
      int r  = (tid >> 3) + it * 32;
      int mg = tid & 7;
      float4 v = *reinterpret_cast<const float4*>(&A[(n0 + r) * NNODE + m0 + mg * 4]);
      AsT[mg * 4 + 0][r] = v.x; AsT[mg * 4 + 1][r] = v.y;
      AsT[mg * 4 + 2][r] = v.z; AsT[mg * 4 + 3][r] = v.w;
    }
    for (int t = tid; t < 32 * 17; t += 256) {
      int mm = t / 17, g = t % 17;
      float4 v = loadX4<SRC>(s64, inp, xbuf, b, m0 + mm, g);
      *reinterpret_cast<float4*>(&Xs[mm][g * 4]) = v;
    }
    __syncthreads();
    #pragma unroll
    for (int mm = 0; mm < 32; ++mm) {
      float a[8];
      #pragma unroll
      for (int i = 0; i < 8; ++i) a[i] = AsT[mm][tr * 8 + i];
      float4 bv = *reinterpret_cast<const float4*>(&Xs[mm][tc * 4]);
      #pragma unroll
      for (int i = 0; i < 8; ++i) {
        acc[i][0] = fmaf(a[i], bv.x, acc[i][0]);
        acc[i][1] = fmaf(a[i], bv.y, acc[i][1]);
        acc[i][2] = fmaf(a[i], bv.z, acc[i][2]);
        acc[i][3] = fmaf(a[i], bv.w, acc[i][3]);
      }
      acce = fmaf(AsT[mm][er], Xs[mm][64 + ec], acce);
    }
    __syncthreads();
  }

  #pragma unroll
  for (int i = 0; i < 8; ++i) {
    int n = n0 + tr * 8 + i;
    float4 v = make_float4(acc[i][0], acc[i][1], acc[i][2], acc[i][3]);
    if (EPI) {
      float4 x0 = loadX4<0>(x0s64, inp, nullptr, b, n, tc);
      v.x = 2.0f * v.x - x0.x; v.y = 2.0f * v.y - x0.y;
      v.z = 2.0f * v.z - x0.z; v.w = 2.0f * v.w - x0.w;
    }
    *reinterpret_cast<float4*>(&Y[((size_t)b * NNODE + n) * NFP + tc * 4]) = v;
  }
  {
    int n = n0 + er;
    float v = acce;
    if (EPI) v = 2.0f * v - inp[(size_t)b * NNODE * 2 + n * 2 + ec];
    Y[((size_t)b * NNODE + n) * NFP + 64 + ec] = v;
  }
}

// out[b][n][:] = act( sum_{f'=0..65,k=0..2} stk[b][n][f'][k] * W[fmap(f')*3+k][:] + bias )
// gate: sigmoid -> rs = r*state (cols<64), u -> uio (cols>=64)
// cand: tanh -> out = u*state + (1-u)*c  (u read from uio == d_out, overwritten)
template<int ISGATE>
__global__ __launch_bounds__(256) void k_applyW(
    const float* __restrict__ s64,
    const float* __restrict__ inp,
    const float* __restrict__ X1buf,
    const float* __restrict__ X2buf,
    const float* __restrict__ W,
    const float* __restrict__ bias,
    const float* __restrict__ state,
    float* __restrict__ rs,
    float* __restrict__ uio,
    float* __restrict__ outp) {
  constexpr int NC  = ISGATE ? 128 : 64;
  constexpr int TCN = NC / 4;            // 32 or 16 col-threads
  constexpr int RP  = 32 / (256 / TCN);  // 4 or 2 rows per thread
  __shared__ float S[3][32][NFP];
  __shared__ float Wl[48][NC];
  const int b   = blockIdx.y;
  const int n0  = blockIdx.x * 32;
  const int tid = threadIdx.x;
  const int tc  = tid % TCN;
  const int tr  = tid / TCN;
  float acc[RP][4];
  #pragma unroll
  for (int i = 0; i < RP; ++i)
    #pragma unroll
    for (int j = 0; j < 4; ++j) acc[i][j] = 0.0f;

  for (int t = tid; t < 32 * 17; t += 256) {
    int r = t / 17, g = t % 17;
    *reinterpret_cast<float4*>(&S[0][r][g * 4]) = loadX4<0>(s64, inp, nullptr, b, n0 + r, g);
    *reinterpret_cast<float4*>(&S[1][r][g * 4]) = loadX4<1>(nullptr, nullptr, X1buf, b, n0 + r, g);
    *reinterpret_cast<float4*>(&S[2][r][g * 4]) = loadX4<1>(nullptr, nullptr, X2buf, b, n0 + r, g);
  }

  for (int fc = 0; fc < 66; fc += 16) {
    int len  = min(16, 66 - fc);
    int rows = len * 3;
    __syncthreads();   // protects S stores (iter 0) and previous Wl reads
    for (int t = tid; t < rows * (NC / 4); t += 256) {
      int rl = t / (NC / 4), g = t % (NC / 4);
      int f = fc + rl / 3, k = rl % 3;
      int fo = (f < 64) ? (f + 2) : (f - 64);
      *reinterpret_cast<float4*>(&Wl[rl][g * 4]) =
          *reinterpret_cast<const float4*>(&W[(size_t)(fo * 3 + k) * NC + g * 4]);
    }
    __syncthreads();
    for (int fl = 0; fl < len; ++fl) {
      #pragma unroll
      for (int k = 0; k < 3; ++k) {
        float a[RP];
        #pragma unroll
        for (int i = 0; i < RP; ++i) a[i] = S[k][tr * RP + i][fc + fl];
        float4 bv = *reinterpret_cast<const float4*>(&Wl[fl * 3 + k][tc * 4]);
        #pragma unroll
        for (int i = 0; i < RP; ++i) {
          acc[i][0] = fmaf(a[i], bv.x, acc[i][0]);
          acc[i][1] = fmaf(a[i], bv.y, acc[i][1]);
          acc[i][2] = fmaf(a[i], bv.z, acc[i][2]);
          acc[i][3] = fmaf(a[i], bv.w, acc[i][3]);
        }
      }
    }
  }

  #pragma unroll
  for (int i = 0; i < RP; ++i) {
    int n = n0 + tr * RP + i;
    size_t base = ((size_t)b * NNODE + n) * ND;
    #pragma unroll
    for (int j = 0; j < 4; ++j) {
      int col = tc * 4 + j;
      float x = acc[i][j] + bias[col];
      if (ISGATE) {
        float v = 1.0f / (1.0f + expf(-x));
        if (col < ND) rs[base + col] = v * s64[base + col];
        else          uio[base + col - ND] = v;
      } else {
        float c  = tanhf(x);
        float u  = uio[base + col];
        float st = state[base + col];
        outp[base + col] = fmaf(u, st - c, c);   // u*st + (1-u)*c
      }
    }
  }
}

extern "C" void kernel_launch(void* const* d_in, const int* in_sizes, int n_in,
                              void* d_out, int out_size, void* d_ws, size_t ws_size,
                              hipStream_t stream) {
  const float* inp   = (const float*)d_in[0];
  const float* state = (const float*)d_in[1];
  const float* adj   = (const float*)d_in[2];
  const float* Wg    = (const float*)d_in[3];
  const float* bg    = (const float*)d_in[4];
  const float* Wc    = (const float*)d_in[5];
  const float* bc    = (const float*)d_in[6];
  float* out = (float*)d_out;
  float* ws  = (float*)d_ws;

  float* dinv = ws;
  float* A    = ws + 512;
  float* X1   = A  + (size_t)NNODE * NNODE;
  float* X2   = X1 + (size_t)NBATCH * NNODE * NFP;
  float* RS   = X2 + (size_t)NBATCH * NNODE * NFP;
  // total ws use: (512 + 262144 + 2*8912896 + 8388608) * 4 B ~= 106 MB

  k_dinv  <<<NNODE, 64,  0, stream>>>(adj, dinv);
  k_buildA<<<NNODE, 256, 0, stream>>>(adj, dinv, A);

  dim3 gs(4, NBATCH);    // diffusion GEMMs: 128-row tiles
  dim3 ga(16, NBATCH);   // apply-W: 32-row tiles

  // gate path
  k_diffstep<0,0><<<gs, 256, 0, stream>>>(A, state, inp, nullptr, nullptr, X1);
  k_diffstep<1,1><<<gs, 256, 0, stream>>>(A, nullptr, inp, X1, state, X2);
  k_applyW<1><<<ga, 256, 0, stream>>>(state, inp, X1, X2, Wg, bg, state, RS, out, nullptr);

  // candidate path (X1c/X2c reuse the gate buffers)
  k_diffstep<0,0><<<gs, 256, 0, stream>>>(A, RS, inp, nullptr, nullptr, X1);
  k_diffstep<1,1><<<gs, 256, 0, stream>>>(A, nullptr, inp, X1, RS, X2);
  k_applyW<0><<<ga, 256, 0, stream>>>(RS, inp, X1, X2, Wc, bc, state, nullptr, out, out);
}

// Round 4
// 267.285 us; speedup vs baseline: 2.7781x; 2.7781x over previous
//
#include <hip/hip_runtime.h>
#include <math.h>

typedef unsigned short u16;
typedef float f32x4 __attribute__((ext_vector_type(4)));
typedef short s16x4 __attribute__((ext_vector_type(4)));
typedef short s16x8 __attribute__((ext_vector_type(8)));

#define AS3 __attribute__((address_space(3)))
#define AS1 __attribute__((address_space(1)))

__device__ __forceinline__ u16 f2bf(float f) {
  unsigned x = __builtin_bit_cast(unsigned, f);
  x += 0x7fffu + ((x >> 16) & 1u);
  return (u16)(x >> 16);
}
__device__ __forceinline__ float bf2f(u16 u) {
  unsigned x = ((unsigned)u) << 16;
  return __builtin_bit_cast(float, x);
}
__device__ __forceinline__ void gload16(const void* g, void* l) {
  __builtin_amdgcn_global_load_lds((const AS1 void*)g, (AS3 void*)l, 16, 0, 0);
}

// ---------------- adjacency preprocessing ----------------
__global__ void k_dinv(const float* __restrict__ adj, float* __restrict__ dinv) {
  int j = blockIdx.x;
  float s = 0.0f;
  for (int i = threadIdx.x; i < 512; i += 64) s += adj[(size_t)j * 512 + i];
  #pragma unroll
  for (int off = 32; off > 0; off >>= 1) s += __shfl_down(s, off);
  if (threadIdx.x == 0) dinv[j] = 1.0f / (1.0f + s);
}

// Ab[n][m] = (adj[m][n] + (n==m)) * dinv[m]   (random-walk transpose), bf16
__global__ void k_buildA(const float* __restrict__ adj, const float* __restrict__ dinv,
                         u16* __restrict__ Ab) {
  int i = blockIdx.x;
  for (int j = threadIdx.x; j < 512; j += 256) {
    float v = adj[(size_t)j * 512 + i] + ((i == j) ? 1.0f : 0.0f);
    Ab[(size_t)i * 512 + j] = f2bf(v * dinv[j]);
  }
}

// state fp32 -> node-major bf16 (flat copy): XG0n[b][n][d]
__global__ void k_prepS(const float* __restrict__ s, u16* __restrict__ d) {
  size_t i = ((size_t)blockIdx.x * 256 + threadIdx.x) * 4;
  f32x4 v = *(const f32x4*)&s[i];
  s16x4 o;
  #pragma unroll
  for (int r = 0; r < 4; ++r) o[r] = (short)f2bf(v[r]);
  *(s16x4*)&d[i] = o;
}

// state fp32 -> f-major bf16: XG0t[(b*64+d)*512 + n]  (64x64 LDS tile transpose)
__global__ __launch_bounds__(256) void k_prepT(const float* __restrict__ s,
                                               u16* __restrict__ Xt) {
  __shared__ float Tl[64][65];
  const int b = blockIdx.y, n0 = blockIdx.x * 64;
  const int tid = threadIdx.x;
  const int r = tid >> 4, c4 = (tid & 15) * 4;
  #pragma unroll
  for (int i = 0; i < 4; ++i) {
    f32x4 v = *(const f32x4*)&s[((size_t)b * 512 + n0 + i * 16 + r) * 64 + c4];
    #pragma unroll
    for (int j = 0; j < 4; ++j) Tl[c4 + j][i * 16 + r] = v[j];
  }
  __syncthreads();
  #pragma unroll
  for (int i = 0; i < 4; ++i) {
    int d = i * 16 + r;
    s16x4 o;
    #pragma unroll
    for (int j = 0; j < 4; ++j) o[j] = (short)f2bf(Tl[d][c4 + j]);
    *(s16x4*)&Xt[((size_t)b * 64 + d) * 512 + n0 + c4] = o;
  }
}

// inp[b][m*2+c] -> Xi0t[(b*2+c)*512 + m]  (bf16, channel-major rows)
__global__ void k_prepI(const float* __restrict__ inp, u16* __restrict__ Xi0t) {
  const int b = blockIdx.x, t = threadIdx.x;
  const int m2 = t * 2;
  f32x4 v = *(const f32x4*)&inp[(size_t)b * 1024 + m2 * 2];
  unsigned p0 = (unsigned)f2bf(v.x) | ((unsigned)f2bf(v.z) << 16);
  unsigned p1 = (unsigned)f2bf(v.y) | ((unsigned)f2bf(v.w) << 16);
  *(unsigned*)&Xi0t[((size_t)b * 2 + 0) * 512 + m2] = p0;
  *(unsigned*)&Xi0t[((size_t)b * 2 + 1) * 512 + m2] = p1;
}

// WT[col][kappa(224)] bf16: kappa<192: f=kappa&63,k1=kappa>>6 -> W[(f+2)*3+k1][col]
// kappa in [192,198): t=kappa-192: k1=t>>1,c=t&1 -> W[c*3+k1][col]; else 0
template<int NC>
__global__ void k_wt(const float* __restrict__ W, u16* __restrict__ WT) {
  int col = blockIdx.x, kap = threadIdx.x;
  if (kap >= 224) return;
  float v = 0.0f;
  if (kap < 192) {
    int f = kap & 63, k1 = kap >> 6;
    v = W[(size_t)((f + 2) * 3 + k1) * NC + col];
  } else if (kap < 198) {
    int t = kap - 192, k1 = t >> 1, c = t & 1;
    v = W[(size_t)(c * 3 + k1) * NC + col];
  }
  WT[(size_t)col * 224 + kap] = f2bf(v);
}

// ---------------- diffusion GEMM (f-major): Yt[R][n] = sum_m Xt[R][m] * Ab[n][m] ----
// R = flat row (b*64+f for batch path, bc for input path). Block: 64 R-rows x 128 nodes.
// A-operand = Xt rows (row-major in k=m), B-operand = Ab rows (col-major in k=m).
// Both LDS tiles [rows][32 m], 16B chunks source-XOR-swizzled by (row&3).
// EPI: y = 2*acc - X0t.  WMODE bit0: write Yt (f-major); bit1: write Yn (node-major).
template<int EPI, int WMODE>
__global__ __launch_bounds__(256) void k_diffF(const u16* __restrict__ Xt,
                                               const u16* __restrict__ Ab,
                                               const u16* __restrict__ X0t,
                                               u16* __restrict__ Yt,
                                               u16* __restrict__ Yn) {
  __shared__ __align__(16) u16 Xl[64 * 32];
  __shared__ __align__(16) u16 Bl[128 * 32];
  const int tid = threadIdx.x;
  const int w = tid >> 6, l = tid & 63, g = l >> 4, l16 = l & 15;
  const int nt0 = blockIdx.x * 128;
  const size_t R0 = (size_t)blockIdx.y * 64;
  f32x4 acc[4][2] = {};

  for (int m0 = 0; m0 < 512; m0 += 32) {
    __syncthreads();
    {
      int r = tid >> 2, p = tid & 3;
      gload16(&Xt[(R0 + r) * 512 + m0 + 8 * (p ^ (r & 3))], &Xl[(w * 64) * 8]);
    }
    #pragma unroll
    for (int pass = 0; pass < 2; ++pass) {
      int s = pass * 256 + tid;
      int r = s >> 2, p = s & 3;
      gload16(&Ab[(size_t)(nt0 + r) * 512 + m0 + 8 * (p ^ (r & 3))],
              &Bl[(pass * 256 + w * 64) * 8]);
    }
    asm volatile("s_waitcnt vmcnt(0)" ::: "memory");
    __syncthreads();

    s16x8 af[4], bf[2];
    #pragma unroll
    for (int mt = 0; mt < 4; ++mt) {
      int r = mt * 16 + l16;
      const char* rowp = (const char*)Xl + r * 64 + 8 * (g & 1);
      int c0 = (g >> 1), c1 = c0 + 2;
      s16x4 lo = *(const s16x4*)(rowp + 16 * (c0 ^ (r & 3)));
      s16x4 hi = *(const s16x4*)(rowp + 16 * (c1 ^ (r & 3)));
      af[mt] = __builtin_shufflevector(lo, hi, 0, 1, 2, 3, 4, 5, 6, 7);
    }
    #pragma unroll
    for (int nt = 0; nt < 2; ++nt) {
      int r = w * 32 + nt * 16 + l16;
      const char* rowp = (const char*)Bl + r * 64 + 8 * (g & 1);
      int c0 = (g >> 1), c1 = c0 + 2;
      s16x4 lo = *(const s16x4*)(rowp + 16 * (c0 ^ (r & 3)));
      s16x4 hi = *(const s16x4*)(rowp + 16 * (c1 ^ (r & 3)));
      bf[nt] = __builtin_shufflevector(lo, hi, 0, 1, 2, 3, 4, 5, 6, 7);
    }
    #pragma unroll
    for (int mt = 0; mt < 4; ++mt)
      #pragma unroll
      for (int nt = 0; nt < 2; ++nt)
        acc[mt][nt] = __builtin_amdgcn_mfma_f32_16x16x32_bf16(af[mt], bf[nt],
                                                              acc[mt][nt], 0, 0, 0);
  }

  #pragma unroll
  for (int mt = 0; mt < 4; ++mt)
    #pragma unroll
    for (int nt = 0; nt < 2; ++nt) {
      int node = nt0 + w * 32 + nt * 16 + l16;
      #pragma unroll
      for (int r = 0; r < 4; ++r) {
        size_t R = R0 + mt * 16 + 4 * g + r;
        size_t idxT = R * 512 + node;
        float v = acc[mt][nt][r];
        if (EPI) v = 2.0f * v - bf2f(X0t[idxT]);
        u16 o = f2bf(v);
        if (WMODE & 1) Yt[idxT] = o;
        if (WMODE & 2) Yn[((R >> 6) * 512 + node) * 64 + (R & 63)] = o;
      }
    }
}

// ---------------- applyW: out[(b,n)][col] = act( stk @ W + bias ), MFMA ----------------
// A-operand = WT rows (out cols), B-operand = S rows (node-major). 7 K-tiles.
// MODE 0: gate r -> XC0n = sigmoid*state (bf16, node-major) + XC0t (f-major).
// MODE 1: gate u -> outp (fp32, temp). MODE 2: cand -> outp = u*state + (1-u)*tanh.
template<int MODE>
__global__ __launch_bounds__(256) void k_applyW(
    const u16* __restrict__ S0b, const u16* __restrict__ S1b, const u16* __restrict__ S2b,
    const float* __restrict__ inp, const u16* __restrict__ Yi1, const u16* __restrict__ Yi2,
    const u16* __restrict__ WT, const float* __restrict__ bias,
    const float* __restrict__ state,
    u16* __restrict__ XC0n, u16* __restrict__ XC0t, float* outp) {
  __shared__ __align__(16) u16 Sl[3][4096];   // [64 rows][64 f], swizzled chunks
  __shared__ __align__(16) u16 St[64 * 36];   // tail k-tile [64 rows][36]
  __shared__ __align__(16) u16 Wl[64 * 224];  // [64 cols][224], swizzled chunks
  const int tid = threadIdx.x;
  const int w = tid >> 6, l = tid & 63, g = l >> 4, l16 = l & 15;
  const int b = blockIdx.y, n0 = blockIdx.x * 64;

  const u16* Sb[3] = {S0b, S1b, S2b};
  #pragma unroll
  for (int k1 = 0; k1 < 3; ++k1)
    #pragma unroll
    for (int it = 0; it < 2; ++it) {
      int s = it * 256 + tid;
      int r = s >> 3, p = s & 7;
      gload16(&Sb[k1][((size_t)b * 512 + n0 + r) * 64 + 8 * (p ^ (r & 7))],
              &Sl[k1][(it * 256 + w * 64) * 8]);
    }
  #pragma unroll
  for (int it = 0; it < 7; ++it) {
    int s = it * 256 + tid;
    int col = s / 28, p = s % 28;
    int c8 = (p < 24) ? (p ^ (col & 7)) : (24 + ((p - 24) ^ (col & 3)));
    gload16(&WT[(size_t)col * 224 + 8 * c8], &Wl[(it * 256 + w * 64) * 8]);
  }
  for (int i = tid; i < 64 * 36; i += 256)
    if ((i % 36) >= 6) St[i] = 0;
  for (int t = tid; t < 384; t += 256) {
    int k1 = t >> 7, rr = (t >> 1) & 63, c = t & 1;
    u16 v;
    if (k1 == 0) v = f2bf(inp[((size_t)b * 512 + n0 + rr) * 2 + c]);
    else {
      const u16* Yk = (k1 == 1) ? Yi1 : Yi2;
      v = Yk[((size_t)b * 2 + c) * 512 + (n0 + rr)];   // f-major Yi
    }
    St[rr * 36 + k1 * 2 + c] = v;
  }
  asm volatile("s_waitcnt vmcnt(0)" ::: "memory");
  __syncthreads();

  f32x4 acc[4] = {};
  const int colr = w * 16 + l16;
  #pragma unroll
  for (int kt = 0; kt < 7; ++kt) {
    s16x8 aw;
    {
      int c0 = kt * 4 + (g >> 1), c1 = c0 + 2;
      int p0 = (c0 < 24) ? (c0 ^ (colr & 7)) : (24 + ((c0 - 24) ^ (colr & 3)));
      int p1 = (c1 < 24) ? (c1 ^ (colr & 7)) : (24 + ((c1 - 24) ^ (colr & 3)));
      const char* rowp = (const char*)Wl + colr * 448 + 8 * (g & 1);
      s16x4 lo = *(const s16x4*)(rowp + 16 * p0);
      s16x4 hi = *(const s16x4*)(rowp + 16 * p1);
      aw = __builtin_shufflevector(lo, hi, 0, 1, 2, 3, 4, 5, 6, 7);
    }
    #pragma unroll
    for (int ns = 0; ns < 4; ++ns) {
      int rn = ns * 16 + l16;
      s16x4 lo, hi;
      if (kt < 6) {
        const int buf = kt >> 1, ft = kt & 1;
        int c0 = ft * 4 + (g >> 1), c1 = c0 + 2;
        const char* rowp = (const char*)Sl[buf] + rn * 128 + 8 * (g & 1);
        lo = *(const s16x4*)(rowp + 16 * (c0 ^ (rn & 7)));
        hi = *(const s16x4*)(rowp + 16 * (c1 ^ (rn & 7)));
      } else {
        const char* rowp = (const char*)St + rn * 72 + 8 * g;
        lo = *(const s16x4*)(rowp);
        hi = *(const s16x4*)(rowp + 32);
      }
      s16x8 bs = __builtin_shufflevector(lo, hi, 0, 1, 2, 3, 4, 5, 6, 7);
      acc[ns] = __builtin_amdgcn_mfma_f32_16x16x32_bf16(aw, bs, acc[ns], 0, 0, 0);
    }
  }

  f32x4 b4 = *(const f32x4*)&bias[w * 16 + 4 * g];
  #pragma unroll
  for (int ns = 0; ns < 4; ++ns) {
    int n = n0 + ns * 16 + l16;
    size_t base = ((size_t)b * 512 + n) * 64 + w * 16 + 4 * g;
    if (MODE == 0) {
      f32x4 st4 = *(const f32x4*)&state[base];
      s16x4 o;
      float ov[4];
      #pragma unroll
      for (int r = 0; r < 4; ++r) {
        float x = acc[ns][r] + b4[r];
        float sg = 1.0f / (1.0f + expf(-x));
        ov[r] = sg * st4[r];
        o[r] = (short)f2bf(ov[r]);
      }
      *(s16x4*)&XC0n[base] = o;
      #pragma unroll
      for (int r = 0; r < 4; ++r)
        XC0t[((size_t)b * 64 + w * 16 + 4 * g + r) * 512 + n] = (u16)o[r];
    } else if (MODE == 1) {
      f32x4 o;
      #pragma unroll
      for (int r = 0; r < 4; ++r) {
        float x = acc[ns][r] + b4[r];
        o[r] = 1.0f / (1.0f + expf(-x));
      }
      *(f32x4*)&outp[base] = o;   // u stashed in d_out
    } else {
      f32x4 u4 = *(const f32x4*)&outp[base];   // read u (same thread overwrites below)
      f32x4 st4 = *(const f32x4*)&state[base];
      f32x4 o;
      #pragma unroll
      for (int r = 0; r < 4; ++r) {
        float c = tanhf(acc[ns][r] + b4[r]);
        o[r] = fmaf(u4[r], st4[r] - c, c);
      }
      *(f32x4*)&outp[base] = o;
    }
  }
}

extern "C" void kernel_launch(void* const* d_in, const int* in_sizes, int n_in,
                              void* d_out, int out_size, void* d_ws, size_t ws_size,
                              hipStream_t stream) {
  const float* inp   = (const float*)d_in[0];
  const float* state = (const float*)d_in[1];
  const float* adj   = (const float*)d_in[2];
  const float* Wg    = (const float*)d_in[3];
  const float* bg    = (const float*)d_in[4];
  const float* Wc    = (const float*)d_in[5];
  const float* bc    = (const float*)d_in[6];
  float* out = (float*)d_out;

  char* p = (char*)d_ws;
  u16* Abf  = (u16*)p; p += 524288;     // Ab[n][m] bf16
  u16* Xi0t = (u16*)p; p += 524288;     // [bc][m]
  u16* Yi1t = (u16*)p; p += 524288;     // [bc][node]
  u16* Yi2t = (u16*)p; p += 524288;
  u16* WTg  = (u16*)p; p += 57344;      // [128][224]
  u16* WTc  = (u16*)p; p += 28672;      // [64][224]
  float* dinv = (float*)p; p += 2048;
  u16* XG0n = (u16*)p; p += 16777216;   // [b][n][64]
  u16* XG0t = (u16*)p; p += 16777216;   // [b*64+f][512]; reused as XC0t later
  u16* XC0n = (u16*)p; p += 16777216;
  u16* X1t  = (u16*)p; p += 16777216;
  u16* X1n  = (u16*)p; p += 16777216;
  u16* X2n  = (u16*)p; p += 16777216;   // total ~98.1 MiB
  u16* XC0t = XG0t;                     // alias: XG0t dead after gate step 2

  k_dinv  <<<512, 64,  0, stream>>>(adj, dinv);
  k_buildA<<<512, 256, 0, stream>>>(adj, dinv, Abf);
  k_prepS <<<8192, 256, 0, stream>>>(state, XG0n);
  k_prepT <<<dim3(8, 256), 256, 0, stream>>>(state, XG0t);
  k_prepI <<<256, 256, 0, stream>>>(inp, Xi0t);
  k_wt<128><<<128, 256, 0, stream>>>(Wg, WTg);
  k_wt<64> <<<64, 256, 0, stream>>>(Wc, WTc);

  // input-column diffusion (batch-shared): rows = 512 bc
  k_diffF<0, 1><<<dim3(4, 8), 256, 0, stream>>>(Xi0t, Abf, nullptr, Yi1t, nullptr);
  k_diffF<1, 1><<<dim3(4, 8), 256, 0, stream>>>(Yi1t, Abf, Xi0t, Yi2t, nullptr);

  // gate path
  k_diffF<0, 3><<<dim3(4, 256), 256, 0, stream>>>(XG0t, Abf, nullptr, X1t, X1n);
  k_diffF<1, 2><<<dim3(4, 256), 256, 0, stream>>>(X1t, Abf, XG0t, nullptr, X2n);
  k_applyW<0><<<dim3(8, 256), 256, 0, stream>>>(XG0n, X1n, X2n, inp, Yi1t, Yi2t,
                                                WTg, bg, state, XC0n, XC0t, out);
  k_applyW<1><<<dim3(8, 256), 256, 0, stream>>>(XG0n, X1n, X2n, inp, Yi1t, Yi2t,
                                                WTg + 64 * 224, bg + 64, state,
                                                nullptr, nullptr, out);

  // candidate path
  k_diffF<0, 3><<<dim3(4, 256), 256, 0, stream>>>(XC0t, Abf, nullptr, X1t, X1n);
  k_diffF<1, 2><<<dim3(4, 256), 256, 0, stream>>>(X1t, Abf, XC0t, nullptr, X2n);
  k_applyW<2><<<dim3(8, 256), 256, 0, stream>>>(XC0n, X1n, X2n, inp, Yi1t, Yi2t,
                                                WTc, bc, state, nullptr, nullptr, out);
}

// Round 5
// 257.841 us; speedup vs baseline: 2.8799x; 1.0366x over previous
//
#include <hip/hip_runtime.h>
#include <math.h>

typedef unsigned short u16;
typedef float f32x4 __attribute__((ext_vector_type(4)));
typedef short s16x4 __attribute__((ext_vector_type(4)));
typedef short s16x8 __attribute__((ext_vector_type(8)));

#define AS3 __attribute__((address_space(3)))
#define AS1 __attribute__((address_space(1)))

__device__ __forceinline__ u16 f2bf(float f) {
  unsigned x = __builtin_bit_cast(unsigned, f);
  x += 0x7fffu + ((x >> 16) & 1u);
  return (u16)(x >> 16);
}
__device__ __forceinline__ float bf2f(u16 u) {
  unsigned x = ((unsigned)u) << 16;
  return __builtin_bit_cast(float, x);
}
__device__ __forceinline__ void gload16(const void* g, void* l) {
  __builtin_amdgcn_global_load_lds((const AS1 void*)g, (AS3 void*)l, 16, 0, 0);
}

// ---------------- adjacency preprocessing ----------------
__global__ void k_dinv(const float* __restrict__ adj, float* __restrict__ dinv) {
  int j = blockIdx.x;
  float s = 0.0f;
  for (int i = threadIdx.x; i < 512; i += 64) s += adj[(size_t)j * 512 + i];
  #pragma unroll
  for (int off = 32; off > 0; off >>= 1) s += __shfl_down(s, off);
  if (threadIdx.x == 0) dinv[j] = 1.0f / (1.0f + s);
}

// Ab[n][m] = (adj[m][n] + (n==m)) * dinv[m]   (random-walk transpose), bf16
__global__ void k_buildA(const float* __restrict__ adj, const float* __restrict__ dinv,
                         u16* __restrict__ Ab) {
  int i = blockIdx.x;
  for (int j = threadIdx.x; j < 512; j += 256) {
    float v = adj[(size_t)j * 512 + i] + ((i == j) ? 1.0f : 0.0f);
    Ab[(size_t)i * 512 + j] = f2bf(v * dinv[j]);
  }
}

// state fp32 -> node-major bf16 (XG0n) AND f-major bf16 (XG0t), one read
__global__ __launch_bounds__(256) void k_prepST(const float* __restrict__ s,
                                                u16* __restrict__ Xn,
                                                u16* __restrict__ Xt) {
  __shared__ float Tl[64][65];
  const int b = blockIdx.y, n0 = blockIdx.x * 64;
  const int tid = threadIdx.x;
  const int r = tid >> 4, c4 = (tid & 15) * 4;
  #pragma unroll
  for (int i = 0; i < 4; ++i) {
    f32x4 v = *(const f32x4*)&s[((size_t)b * 512 + n0 + i * 16 + r) * 64 + c4];
    s16x4 o;
    #pragma unroll
    for (int j = 0; j < 4; ++j) { Tl[c4 + j][i * 16 + r] = v[j]; o[j] = (short)f2bf(v[j]); }
    *(s16x4*)&Xn[((size_t)b * 512 + n0 + i * 16 + r) * 64 + c4] = o;
  }
  __syncthreads();
  #pragma unroll
  for (int i = 0; i < 4; ++i) {
    int d = i * 16 + r;
    s16x4 o;
    #pragma unroll
    for (int j = 0; j < 4; ++j) o[j] = (short)f2bf(Tl[d][c4 + j]);
    *(s16x4*)&Xt[((size_t)b * 64 + d) * 512 + n0 + c4] = o;
  }
}

// inp[b][m*2+c] -> Xi0t[(b*2+c)*512 + m]  (bf16, channel-major rows; Xi0t = XAll0t tail)
__global__ void k_prepI(const float* __restrict__ inp, u16* __restrict__ Xi0t) {
  const int b = blockIdx.x, t = threadIdx.x;
  const int m2 = t * 2;
  f32x4 v = *(const f32x4*)&inp[(size_t)b * 1024 + m2 * 2];
  unsigned p0 = (unsigned)f2bf(v.x) | ((unsigned)f2bf(v.z) << 16);
  unsigned p1 = (unsigned)f2bf(v.y) | ((unsigned)f2bf(v.w) << 16);
  *(unsigned*)&Xi0t[((size_t)b * 2 + 0) * 512 + m2] = p0;
  *(unsigned*)&Xi0t[((size_t)b * 2 + 1) * 512 + m2] = p1;
}

// WTp[col][kt][g][j] (224 u16/col): per-thread MFMA A-fragment, one 16B load.
// kappa(kt,g,j) = 32*kt + 4*g + (j<4 ? j : j+12); kappa<192: f=kappa&63,k1=kappa>>6
//   -> W[(f+2)*3+k1][col]; 192<=kappa<198: t=kappa-192,k1=t>>1,c=t&1 -> W[c*3+k1][col]; else 0
template<int NC>
__global__ void k_wtp(const float* __restrict__ W, u16* __restrict__ WTp) {
  int col = blockIdx.x, tid = threadIdx.x;
  if (tid >= 224) return;
  int kt = tid >> 5, g = (tid >> 3) & 3, j = tid & 7;
  int kappa = 32 * kt + 4 * g + ((j < 4) ? j : j + 12);
  float v = 0.0f;
  if (kappa < 192) {
    int f = kappa & 63, k1 = kappa >> 6;
    v = W[(size_t)((f + 2) * 3 + k1) * NC + col];
  } else if (kappa < 198) {
    int t = kappa - 192, k1 = t >> 1, c = t & 1;
    v = W[(size_t)(c * 3 + k1) * NC + col];
  }
  WTp[(size_t)col * 224 + tid] = f2bf(v);
}

// ---------------- diffusion GEMM (f-major, double-buffered) ----------------
// Yt[R][n] = sum_m Xt[R][m] * Ab[n][m].  Block 64 R x 128 nodes, 4 waves, BK=32.
// Rows R >= 16384 are "input rows": always write Yt only.
// WTB: batch rows write Yt; WNB: batch rows write Yn (node-major [R/64][node][64]).
template<int EPI, int WTB, int WNB>
__global__ __launch_bounds__(256) void k_diffF(const u16* __restrict__ Xt,
                                               const u16* __restrict__ Ab,
                                               const u16* __restrict__ X0t,
                                               u16* __restrict__ Yt,
                                               u16* __restrict__ Yn) {
  __shared__ __align__(16) u16 Xl[2][64 * 32];
  __shared__ __align__(16) u16 Bl[2][128 * 32];
  const int tid = threadIdx.x;
  const int w = tid >> 6, l = tid & 63, g = l >> 4, l16 = l & 15;
  const int nt0 = blockIdx.x * 128;
  const size_t R0 = (size_t)blockIdx.y * 64;
  const bool isInput = (R0 >= 16384);
  f32x4 acc[4][2] = {};

  const int sr = tid >> 2, sp = tid & 3;
  const int s2 = 256 + tid, r2 = s2 >> 2, p2 = s2 & 3;

#define STAGE(BUF, M0)                                                         \
  {                                                                            \
    gload16(&Xt[(R0 + sr) * 512 + (M0) + 8 * (sp ^ (sr & 3))],                 \
            &Xl[BUF][(w * 64) * 8]);                                           \
    gload16(&Ab[(size_t)(nt0 + sr) * 512 + (M0) + 8 * (sp ^ (sr & 3))],        \
            &Bl[BUF][(w * 64) * 8]);                                           \
    gload16(&Ab[(size_t)(nt0 + r2) * 512 + (M0) + 8 * (p2 ^ (r2 & 3))],        \
            &Bl[BUF][(256 + w * 64) * 8]);                                     \
  }

  STAGE(0, 0);
  #pragma unroll
  for (int it = 0; it < 16; ++it) {
    const int cur = it & 1;
    if (it < 15) {
      if (cur == 0) STAGE(1, (it + 1) * 32)
      else          STAGE(0, (it + 1) * 32)
      asm volatile("s_waitcnt vmcnt(3)" ::: "memory");
    } else {
      asm volatile("s_waitcnt vmcnt(0)" ::: "memory");
    }
    __builtin_amdgcn_s_barrier();
    __builtin_amdgcn_sched_barrier(0);

    s16x8 af[4], bf[2];
    #pragma unroll
    for (int mt = 0; mt < 4; ++mt) {
      int r = mt * 16 + l16;
      const char* rowp = (const char*)&Xl[cur][0] + r * 64 + 8 * (g & 1);
      int c0 = (g >> 1), c1 = c0 + 2;
      s16x4 lo = *(const s16x4*)(rowp + 16 * (c0 ^ (r & 3)));
      s16x4 hi = *(const s16x4*)(rowp + 16 * (c1 ^ (r & 3)));
      af[mt] = __builtin_shufflevector(lo, hi, 0, 1, 2, 3, 4, 5, 6, 7);
    }
    #pragma unroll
    for (int nt = 0; nt < 2; ++nt) {
      int r = w * 32 + nt * 16 + l16;
      const char* rowp = (const char*)&Bl[cur][0] + r * 64 + 8 * (g & 1);
      int c0 = (g >> 1), c1 = c0 + 2;
      s16x4 lo = *(const s16x4*)(rowp + 16 * (c0 ^ (r & 3)));
      s16x4 hi = *(const s16x4*)(rowp + 16 * (c1 ^ (r & 3)));
      bf[nt] = __builtin_shufflevector(lo, hi, 0, 1, 2, 3, 4, 5, 6, 7);
    }
    #pragma unroll
    for (int mt = 0; mt < 4; ++mt)
      #pragma unroll
      for (int nt = 0; nt < 2; ++nt)
        acc[mt][nt] = __builtin_amdgcn_mfma_f32_16x16x32_bf16(af[mt], bf[nt],
                                                              acc[mt][nt], 0, 0, 0);
    __builtin_amdgcn_s_barrier();
    __builtin_amdgcn_sched_barrier(0);
  }
#undef STAGE

  #pragma unroll
  for (int mt = 0; mt < 4; ++mt)
    #pragma unroll
    for (int nt = 0; nt < 2; ++nt) {
      int node = nt0 + w * 32 + nt * 16 + l16;
      #pragma unroll
      for (int r = 0; r < 4; ++r) {
        size_t R = R0 + mt * 16 + 4 * g + r;
        size_t idxT = R * 512 + node;
        float v = acc[mt][nt][r];
        if (EPI) v = 2.0f * v - bf2f(X0t[idxT]);
        u16 o = f2bf(v);
        if (WTB || isInput) Yt[idxT] = o;
        if (WNB && !isInput) Yn[((R >> 6) * 512 + node) * 64 + (R & 63)] = o;
      }
    }
}

// ---------------- fused gate applyW (r and u halves): NC=128 ----------------
// A-operand = WTp rows (out cols, in registers); B-operand = S rows (node-major).
// r: sigmoid -> XC0n (node-major bf16) + XC0t (f-major).  u: sigmoid -> outp fp32.
__global__ __launch_bounds__(256) void k_applyG(
    const u16* __restrict__ S0b, const u16* __restrict__ S1b, const u16* __restrict__ S2b,
    const float* __restrict__ inp, const u16* __restrict__ Yi1, const u16* __restrict__ Yi2,
    const u16* __restrict__ WTp, const float* __restrict__ bias,
    u16* __restrict__ XC0n, u16* __restrict__ XC0t, float* __restrict__ outp) {
  __shared__ __align__(16) u16 Sl[3][4096];   // [64 rows][64 f], swizzled chunks
  __shared__ __align__(16) u16 St[64 * 36];   // tail k-tile [64 rows][36]
  const int tid = threadIdx.x;
  const int w = tid >> 6, l = tid & 63, g = l >> 4, l16 = l & 15;
  const int b = blockIdx.y, n0 = blockIdx.x * 64;
  const int colr = w * 16 + l16;

  const u16* Sb[3] = {S0b, S1b, S2b};
  #pragma unroll
  for (int k1 = 0; k1 < 3; ++k1)
    #pragma unroll
    for (int it = 0; it < 2; ++it) {
      int s = it * 256 + tid;
      int r = s >> 3, p = s & 7;
      gload16(&Sb[k1][((size_t)b * 512 + n0 + r) * 64 + 8 * (p ^ (r & 7))],
              &Sl[k1][(it * 256 + w * 64) * 8]);
    }
  // W fragments -> registers (one 16B load each, L2-hot)
  s16x8 aw[7][2];
  {
    const u16* w0 = WTp + (size_t)colr * 224 + g * 8;
    const u16* w1 = WTp + (size_t)(colr + 64) * 224 + g * 8;
    #pragma unroll
    for (int kt = 0; kt < 7; ++kt) {
      aw[kt][0] = *(const s16x8*)&w0[kt * 32];
      aw[kt][1] = *(const s16x8*)&w1[kt * 32];
    }
  }
  for (int i = tid; i < 64 * 36; i += 256)
    if ((i % 36) >= 6) St[i] = 0;
  for (int t = tid; t < 384; t += 256) {
    int k1 = t >> 7, rr = (t >> 1) & 63, c = t & 1;
    u16 v;
    if (k1 == 0) v = f2bf(inp[((size_t)b * 512 + n0 + rr) * 2 + c]);
    else {
      const u16* Yk = (k1 == 1) ? Yi1 : Yi2;
      v = Yk[((size_t)b * 2 + c) * 512 + (n0 + rr)];
    }
    St[rr * 36 + k1 * 2 + c] = v;
  }
  asm volatile("s_waitcnt vmcnt(0)" ::: "memory");
  __syncthreads();

  f32x4 acc0[4] = {}, acc1[4] = {};
  #pragma unroll
  for (int kt = 0; kt < 7; ++kt) {
    #pragma unroll
    for (int ns = 0; ns < 4; ++ns) {
      int rn = ns * 16 + l16;
      s16x4 lo, hi;
      if (kt < 6) {
        const int buf = kt >> 1, ft = kt & 1;
        int c0 = ft * 4 + (g >> 1), c1 = c0 + 2;
        const char* rowp = (const char*)Sl[buf] + rn * 128 + 8 * (g & 1);
        lo = *(const s16x4*)(rowp + 16 * (c0 ^ (rn & 7)));
        hi = *(const s16x4*)(rowp + 16 * (c1 ^ (rn & 7)));
      } else {
        const char* rowp = (const char*)St + rn * 72 + 8 * g;
        lo = *(const s16x4*)(rowp);
        hi = *(const s16x4*)(rowp + 32);
      }
      s16x8 bs = __builtin_shufflevector(lo, hi, 0, 1, 2, 3, 4, 5, 6, 7);
      acc0[ns] = __builtin_amdgcn_mfma_f32_16x16x32_bf16(aw[kt][0], bs, acc0[ns], 0, 0, 0);
      acc1[ns] = __builtin_amdgcn_mfma_f32_16x16x32_bf16(aw[kt][1], bs, acc1[ns], 0, 0, 0);
    }
  }

  f32x4 b4r = *(const f32x4*)&bias[w * 16 + 4 * g];
  f32x4 b4u = *(const f32x4*)&bias[64 + w * 16 + 4 * g];
  const int chk = 2 * w + (g >> 1);
  #pragma unroll
  for (int ns = 0; ns < 4; ++ns) {
    int rn = ns * 16 + l16;
    int n = n0 + rn;
    size_t base = ((size_t)b * 512 + n) * 64 + w * 16 + 4 * g;
    // state bf16 from staged Sl[0]
    const char* srow = (const char*)Sl[0] + rn * 128 + 8 * (g & 1);
    s16x4 st4 = *(const s16x4*)(srow + 16 * (chk ^ (rn & 7)));
    s16x4 o;
    #pragma unroll
    for (int r = 0; r < 4; ++r) {
      float x = acc0[ns][r] + b4r[r];
      float sg = 1.0f / (1.0f + expf(-x));
      o[r] = (short)f2bf(sg * bf2f((u16)st4[r]));
    }
    *(s16x4*)&XC0n[base] = o;
    #pragma unroll
    for (int r = 0; r < 4; ++r)
      XC0t[((size_t)b * 64 + w * 16 + 4 * g + r) * 512 + n] = (u16)o[r];
    f32x4 uo;
    #pragma unroll
    for (int r = 0; r < 4; ++r) {
      float x = acc1[ns][r] + b4u[r];
      uo[r] = 1.0f / (1.0f + expf(-x));
    }
    *(f32x4*)&outp[base] = uo;   // u stashed in d_out
  }
}

// ---------------- candidate applyW: NC=64, out = u*state + (1-u)*tanh ----------------
__global__ __launch_bounds__(256) void k_applyC(
    const u16* __restrict__ S0b, const u16* __restrict__ S1b, const u16* __restrict__ S2b,
    const float* __restrict__ inp, const u16* __restrict__ Yi1, const u16* __restrict__ Yi2,
    const u16* __restrict__ WTp, const float* __restrict__ bias,
    const float* __restrict__ state, float* __restrict__ outp) {
  __shared__ __align__(16) u16 Sl[3][4096];
  __shared__ __align__(16) u16 St[64 * 36];
  const int tid = threadIdx.x;
  const int w = tid >> 6, l = tid & 63, g = l >> 4, l16 = l & 15;
  const int b = blockIdx.y, n0 = blockIdx.x * 64;
  const int colr = w * 16 + l16;

  const u16* Sb[3] = {S0b, S1b, S2b};
  #pragma unroll
  for (int k1 = 0; k1 < 3; ++k1)
    #pragma unroll
    for (int it = 0; it < 2; ++it) {
      int s = it * 256 + tid;
      int r = s >> 3, p = s & 7;
      gload16(&Sb[k1][((size_t)b * 512 + n0 + r) * 64 + 8 * (p ^ (r & 7))],
              &Sl[k1][(it * 256 + w * 64) * 8]);
    }
  s16x8 aw[7];
  {
    const u16* w0 = WTp + (size_t)colr * 224 + g * 8;
    #pragma unroll
    for (int kt = 0; kt < 7; ++kt) aw[kt] = *(const s16x8*)&w0[kt * 32];
  }
  for (int i = tid; i < 64 * 36; i += 256)
    if ((i % 36) >= 6) St[i] = 0;
  for (int t = tid; t < 384; t += 256) {
    int k1 = t >> 7, rr = (t >> 1) & 63, c = t & 1;
    u16 v;
    if (k1 == 0) v = f2bf(inp[((size_t)b * 512 + n0 + rr) * 2 + c]);
    else {
      const u16* Yk = (k1 == 1) ? Yi1 : Yi2;
      v = Yk[((size_t)b * 2 + c) * 512 + (n0 + rr)];
    }
    St[rr * 36 + k1 * 2 + c] = v;
  }
  asm volatile("s_waitcnt vmcnt(0)" ::: "memory");
  __syncthreads();

  f32x4 acc[4] = {};
  #pragma unroll
  for (int kt = 0; kt < 7; ++kt) {
    #pragma unroll
    for (int ns = 0; ns < 4; ++ns) {
      int rn = ns * 16 + l16;
      s16x4 lo, hi;
      if (kt < 6) {
        const int buf = kt >> 1, ft = kt & 1;
        int c0 = ft * 4 + (g >> 1), c1 = c0 + 2;
        const char* rowp = (const char*)Sl[buf] + rn * 128 + 8 * (g & 1);
        lo = *(const s16x4*)(rowp + 16 * (c0 ^ (rn & 7)));
        hi = *(const s16x4*)(rowp + 16 * (c1 ^ (rn & 7)));
      } else {
        const char* rowp = (const char*)St + rn * 72 + 8 * g;
        lo = *(const s16x4*)(rowp);
        hi = *(const s16x4*)(rowp + 32);
      }
      s16x8 bs = __builtin_shufflevector(lo, hi, 0, 1, 2, 3, 4, 5, 6, 7);
      acc[ns] = __builtin_amdgcn_mfma_f32_16x16x32_bf16(aw[kt], bs, acc[ns], 0, 0, 0);
    }
  }

  f32x4 b4 = *(const f32x4*)&bias[w * 16 + 4 * g];
  #pragma unroll
  for (int ns = 0; ns < 4; ++ns) {
    int n = n0 + ns * 16 + l16;
    size_t base = ((size_t)b * 512 + n) * 64 + w * 16 + 4 * g;
    f32x4 u4 = *(const f32x4*)&outp[base];
    f32x4 st4 = *(const f32x4*)&state[base];
    f32x4 o;
    #pragma unroll
    for (int r = 0; r < 4; ++r) {
      float c = tanhf(acc[ns][r] + b4[r]);
      o[r] = fmaf(u4[r], st4[r] - c, c);
    }
    *(f32x4*)&outp[base] = o;
  }
}

extern "C" void kernel_launch(void* const* d_in, const int* in_sizes, int n_in,
                              void* d_out, int out_size, void* d_ws, size_t ws_size,
                              hipStream_t stream) {
  const float* inp   = (const float*)d_in[0];
  const float* state = (const float*)d_in[1];
  const float* adj   = (const float*)d_in[2];
  const float* Wg    = (const float*)d_in[3];
  const float* bg    = (const float*)d_in[4];
  const float* Wc    = (const float*)d_in[5];
  const float* bc    = (const float*)d_in[6];
  float* out = (float*)d_out;

  char* p = (char*)d_ws;
  u16* Abf    = (u16*)p; p += 524288;      // Ab[n][m]
  u16* XAll0t = (u16*)p; p += 17301504;    // [16896][512]: XG0t rows 0..16383 (later XC0t), Xi0t tail
  u16* X1t    = (u16*)p; p += 17301504;    // [16896][512]: X1t batch + Yi1t tail
  u16* Yi2t   = (u16*)p; p += 524288;      // [512][512]
  u16* WTpg   = (u16*)p; p += 57344;       // [128][224] permuted
  u16* WTpc   = (u16*)p; p += 28672;       // [64][224]
  float* dinv = (float*)p; p += 2048;
  u16* XG0n   = (u16*)p; p += 16777216;    // [b][n][64]
  u16* XC0n   = (u16*)p; p += 16777216;
  u16* X1n    = (u16*)p; p += 16777216;
  u16* X2n    = (u16*)p; p += 16777216;    // total ~98.1 MB
  u16* Xi0t   = XAll0t + (size_t)16384 * 512;
  u16* XC0t   = XAll0t;                    // alias: XG0t dead after gate hop 2
  u16* Yi1t   = X1t + (size_t)16384 * 512;
  u16* Yi2off = Yi2t - (size_t)16384 * 512;  // Yt base for hop2 (only R>=16384 deref'd)

  k_dinv   <<<512, 64,  0, stream>>>(adj, dinv);
  k_buildA <<<512, 256, 0, stream>>>(adj, dinv, Abf);
  k_prepST <<<dim3(8, 256), 256, 0, stream>>>(state, XG0n, XAll0t);
  k_prepI  <<<256, 256, 0, stream>>>(inp, Xi0t);
  k_wtp<128><<<128, 256, 0, stream>>>(Wg, WTpg);
  k_wtp<64> <<<64, 256, 0, stream>>>(Wc, WTpc);

  // gate path (input rows folded in: grid y = 264 covers 16384 batch + 512 input rows)
  k_diffF<0, 1, 1><<<dim3(4, 264), 256, 0, stream>>>(XAll0t, Abf, nullptr, X1t, X1n);
  k_diffF<1, 0, 1><<<dim3(4, 264), 256, 0, stream>>>(X1t, Abf, XAll0t, Yi2off, X2n);
  k_applyG<<<dim3(8, 256), 256, 0, stream>>>(XG0n, X1n, X2n, inp, Yi1t, Yi2t,
                                             WTpg, bg, XC0n, XC0t, out);

  // candidate path (batch rows only; input diffusion reused)
  k_diffF<0, 1, 1><<<dim3(4, 256), 256, 0, stream>>>(XC0t, Abf, nullptr, X1t, X1n);
  k_diffF<1, 0, 1><<<dim3(4, 256), 256, 0, stream>>>(X1t, Abf, XC0t, Yi2off, X2n);
  k_applyC<<<dim3(8, 256), 256, 0, stream>>>(XC0n, X1n, X2n, inp, Yi1t, Yi2t,
                                             WTpc, bc, state, out);
}

// Round 6
// 202.912 us; speedup vs baseline: 3.6595x; 1.2707x over previous
//
#include <hip/hip_runtime.h>
#include <math.h>

typedef unsigned short u16;
typedef float f32x4 __attribute__((ext_vector_type(4)));
typedef short s16x4 __attribute__((ext_vector_type(4)));
typedef short s16x8 __attribute__((ext_vector_type(8)));

#define AS3 __attribute__((address_space(3)))
#define AS1 __attribute__((address_space(1)))

__device__ __forceinline__ u16 f2bf(float f) {
  unsigned x = __builtin_bit_cast(unsigned, f);
  x += 0x7fffu + ((x >> 16) & 1u);
  return (u16)(x >> 16);
}
__device__ __forceinline__ float bf2f(u16 u) {
  unsigned x = ((unsigned)u) << 16;
  return __builtin_bit_cast(float, x);
}
__device__ __forceinline__ void gload16(const void* g, void* l) {
  __builtin_amdgcn_global_load_lds((const AS1 void*)g, (AS3 void*)l, 16, 0, 0);
}

// ---------------- adjacency preprocessing ----------------
__global__ void k_dinv(const float* __restrict__ adj, float* __restrict__ dinv) {
  int j = blockIdx.x;
  float s = 0.0f;
  for (int i = threadIdx.x; i < 512; i += 64) s += adj[(size_t)j * 512 + i];
  #pragma unroll
  for (int off = 32; off > 0; off >>= 1) s += __shfl_down(s, off);
  if (threadIdx.x == 0) dinv[j] = 1.0f / (1.0f + s);
}

// Ab[n][m] = (adj[m][n] + (n==m)) * dinv[m]   (random-walk transpose), bf16
__global__ void k_buildA(const float* __restrict__ adj, const float* __restrict__ dinv,
                         u16* __restrict__ Ab) {
  int i = blockIdx.x;
  for (int j = threadIdx.x; j < 512; j += 256) {
    float v = adj[(size_t)j * 512 + i] + ((i == j) ? 1.0f : 0.0f);
    Ab[(size_t)i * 512 + j] = f2bf(v * dinv[j]);
  }
}

// state fp32 -> node-major bf16 (XG0n) AND f-major bf16 (XG0t), one read
__global__ __launch_bounds__(256) void k_prepST(const float* __restrict__ s,
                                                u16* __restrict__ Xn,
                                                u16* __restrict__ Xt) {
  __shared__ float Tl[64][65];
  const int b = blockIdx.y, n0 = blockIdx.x * 64;
  const int tid = threadIdx.x;
  const int r = tid >> 4, c4 = (tid & 15) * 4;
  #pragma unroll
  for (int i = 0; i < 4; ++i) {
    f32x4 v = *(const f32x4*)&s[((size_t)b * 512 + n0 + i * 16 + r) * 64 + c4];
    s16x4 o;
    #pragma unroll
    for (int j = 0; j < 4; ++j) { Tl[c4 + j][i * 16 + r] = v[j]; o[j] = (short)f2bf(v[j]); }
    *(s16x4*)&Xn[((size_t)b * 512 + n0 + i * 16 + r) * 64 + c4] = o;
  }
  __syncthreads();
  #pragma unroll
  for (int i = 0; i < 4; ++i) {
    int d = i * 16 + r;
    s16x4 o;
    #pragma unroll
    for (int j = 0; j < 4; ++j) o[j] = (short)f2bf(Tl[d][c4 + j]);
    *(s16x4*)&Xt[((size_t)b * 64 + d) * 512 + n0 + c4] = o;
  }
}

// inp[b][m*2+c] -> Xi0t[(b*2+c)*512 + m]  (bf16, channel-major rows; Xi0t = XAll0t tail)
__global__ void k_prepI(const float* __restrict__ inp, u16* __restrict__ Xi0t) {
  const int b = blockIdx.x, t = threadIdx.x;
  const int m2 = t * 2;
  f32x4 v = *(const f32x4*)&inp[(size_t)b * 1024 + m2 * 2];
  unsigned p0 = (unsigned)f2bf(v.x) | ((unsigned)f2bf(v.z) << 16);
  unsigned p1 = (unsigned)f2bf(v.y) | ((unsigned)f2bf(v.w) << 16);
  *(unsigned*)&Xi0t[((size_t)b * 2 + 0) * 512 + m2] = p0;
  *(unsigned*)&Xi0t[((size_t)b * 2 + 1) * 512 + m2] = p1;
}

// WTp[col][kt][g][j] (224 u16/col): per-thread MFMA A-fragment, one 16B load.
template<int NC>
__global__ void k_wtp(const float* __restrict__ W, u16* __restrict__ WTp) {
  int col = blockIdx.x, tid = threadIdx.x;
  if (tid >= 224) return;
  int kt = tid >> 5, g = (tid >> 3) & 3, j = tid & 7;
  int kappa = 32 * kt + 4 * g + ((j < 4) ? j : j + 12);
  float v = 0.0f;
  if (kappa < 192) {
    int f = kappa & 63, k1 = kappa >> 6;
    v = W[(size_t)((f + 2) * 3 + k1) * NC + col];
  } else if (kappa < 198) {
    int t = kappa - 192, k1 = t >> 1, c = t & 1;
    v = W[(size_t)(c * 3 + k1) * NC + col];
  }
  WTp[(size_t)col * 224 + tid] = f2bf(v);
}

// ---------------- diffusion GEMM: Yt[R][n] = sum_m Xt[R][m]*Ab[n][m] ----------------
// Block 128R x 128n, 4 waves (2 Rg x 2 ng), BK=32, double-buffered.
// Epilogue: Yn packed 8B stores; Yt via LDS bounce (coalesced 16B); EPI X0 via LDS tile.
template<int EPI, int WTB, int WNB>
__global__ __launch_bounds__(256, 3) void k_diffB(const u16* __restrict__ Xt,
                                                  const u16* __restrict__ Ab,
                                                  const u16* __restrict__ X0t,
                                                  u16* __restrict__ Yt,
                                                  u16* __restrict__ Yn) {
  __shared__ __align__(16) u16 SB[16384];  // XL dbuf @0..8191, AbL dbuf @8192..; epi/bounce: full
  const int tid = threadIdx.x;
  const int w = tid >> 6, l = tid & 63, g = l >> 4, l16 = l & 15;
  const int Rg = w >> 1, ng = w & 1;
  const int nt0 = blockIdx.x * 128;
  const size_t R0 = (size_t)blockIdx.y * 128;
  const bool isInput = (R0 >= 16384);
  f32x4 acc[4][4] = {};

#define STAGE(BUF, M0)                                                            \
  {                                                                               \
    _Pragma("unroll")                                                             \
    for (int i_ = 0; i_ < 2; ++i_) {                                              \
      int s_ = i_ * 256 + tid, r_ = s_ >> 2, p_ = s_ & 3;                         \
      gload16(&Xt[(R0 + r_) * 512 + (M0) + 8 * (p_ ^ (r_ & 3))],                  \
              &SB[(BUF) * 4096 + s_ * 8]);                                        \
      gload16(&Ab[(size_t)(nt0 + r_) * 512 + (M0) + 8 * (p_ ^ (r_ & 3))],         \
              &SB[8192 + (BUF) * 4096 + s_ * 8]);                                 \
    }                                                                             \
  }

  STAGE(0, 0);
  #pragma unroll
  for (int it = 0; it < 16; ++it) {
    const int cur = it & 1;
    if (it < 15) {
      if (cur == 0) STAGE(1, (it + 1) * 32)
      else          STAGE(0, (it + 1) * 32)
      asm volatile("s_waitcnt vmcnt(4)" ::: "memory");
    } else {
      asm volatile("s_waitcnt vmcnt(0)" ::: "memory");
    }
    __builtin_amdgcn_s_barrier();
    __builtin_amdgcn_sched_barrier(0);

    const u16* XL = &SB[cur * 4096];
    const u16* AL = &SB[8192 + cur * 4096];
    s16x8 af[4], bf[4];
    #pragma unroll
    for (int mt = 0; mt < 4; ++mt) {
      int r = Rg * 64 + mt * 16 + l16;
      const char* rowp = (const char*)XL + r * 64 + 8 * (g & 1);
      int c0 = (g >> 1), c1 = c0 + 2;
      s16x4 lo = *(const s16x4*)(rowp + 16 * (c0 ^ (r & 3)));
      s16x4 hi = *(const s16x4*)(rowp + 16 * (c1 ^ (r & 3)));
      af[mt] = __builtin_shufflevector(lo, hi, 0, 1, 2, 3, 4, 5, 6, 7);
    }
    #pragma unroll
    for (int nt = 0; nt < 4; ++nt) {
      int r = ng * 64 + nt * 16 + l16;
      const char* rowp = (const char*)AL + r * 64 + 8 * (g & 1);
      int c0 = (g >> 1), c1 = c0 + 2;
      s16x4 lo = *(const s16x4*)(rowp + 16 * (c0 ^ (r & 3)));
      s16x4 hi = *(const s16x4*)(rowp + 16 * (c1 ^ (r & 3)));
      bf[nt] = __builtin_shufflevector(lo, hi, 0, 1, 2, 3, 4, 5, 6, 7);
    }
    #pragma unroll
    for (int mt = 0; mt < 4; ++mt)
      #pragma unroll
      for (int nt = 0; nt < 4; ++nt)
        acc[mt][nt] = __builtin_amdgcn_mfma_f32_16x16x32_bf16(af[mt], bf[nt],
                                                              acc[mt][nt], 0, 0, 0);
    __builtin_amdgcn_s_barrier();
    __builtin_amdgcn_sched_barrier(0);
  }
#undef STAGE

  if (EPI) {
    // stage X0 tile [128R][128n] (32 KB) into SB via direct-to-LDS
    #pragma unroll
    for (int i = 0; i < 8; ++i) {
      int s = i * 256 + tid, r = s >> 4, c = s & 15;
      gload16(&X0t[(R0 + r) * 512 + nt0 + c * 8], &SB[s * 8]);
    }
    asm volatile("s_waitcnt vmcnt(0)" ::: "memory");
    __builtin_amdgcn_s_barrier();
    #pragma unroll
    for (int mt = 0; mt < 4; ++mt)
      #pragma unroll
      for (int nt = 0; nt < 4; ++nt) {
        int nl = ng * 64 + nt * 16 + l16;
        #pragma unroll
        for (int rr = 0; rr < 4; ++rr) {
          int Rl = Rg * 64 + mt * 16 + 4 * g + rr;
          acc[mt][nt][rr] = 2.0f * acc[mt][nt][rr] - bf2f(SB[Rl * 128 + nl]);
        }
      }
  }

  if (WNB && !isInput) {
    #pragma unroll
    for (int mt = 0; mt < 4; ++mt)
      #pragma unroll
      for (int nt = 0; nt < 4; ++nt) {
        size_t R = R0 + Rg * 64 + mt * 16 + 4 * g;
        int n = nt0 + ng * 64 + nt * 16 + l16;
        s16x4 o;
        #pragma unroll
        for (int rr = 0; rr < 4; ++rr) o[rr] = (short)f2bf(acc[mt][nt][rr]);
        *(s16x4*)&Yn[((R >> 6) * 512 + n) * 64 + (R & 63)] = o;
      }
  }

  if (WTB || isInput) {
    if (EPI) __syncthreads();   // SB reuse: X0 tile -> bounce
    #pragma unroll
    for (int mt = 0; mt < 4; ++mt)
      #pragma unroll
      for (int nt = 0; nt < 4; ++nt) {
        int nl = ng * 64 + nt * 16 + l16;
        #pragma unroll
        for (int rr = 0; rr < 4; ++rr) {
          int Rl = Rg * 64 + mt * 16 + 4 * g + rr;
          SB[Rl * 128 + nl] = f2bf(acc[mt][nt][rr]);
        }
      }
    __syncthreads();
    #pragma unroll
    for (int i = 0; i < 8; ++i) {
      int s = i * 256 + tid, r = s >> 4, c = s & 15;
      *(s16x8*)&Yt[(R0 + r) * 512 + nt0 + c * 8] = *(const s16x8*)&SB[r * 128 + c * 8];
    }
  }
}

// ---------------- fused gate applyW (r and u halves): NC=128 ----------------
__global__ __launch_bounds__(256) void k_applyG(
    const u16* __restrict__ S0b, const u16* __restrict__ S1b, const u16* __restrict__ S2b,
    const float* __restrict__ inp, const u16* __restrict__ Yi1, const u16* __restrict__ Yi2,
    const u16* __restrict__ WTp, const float* __restrict__ bias,
    u16* __restrict__ XC0n, u16* __restrict__ XC0t, u16* __restrict__ Ub) {
  __shared__ __align__(16) u16 Sl[3][4096];
  __shared__ __align__(16) u16 St[64 * 36];
  const int tid = threadIdx.x;
  const int w = tid >> 6, l = tid & 63, g = l >> 4, l16 = l & 15;
  const int b = blockIdx.y, n0 = blockIdx.x * 64;
  const int colr = w * 16 + l16;

  const u16* Sb[3] = {S0b, S1b, S2b};
  #pragma unroll
  for (int k1 = 0; k1 < 3; ++k1)
    #pragma unroll
    for (int it = 0; it < 2; ++it) {
      int s = it * 256 + tid;
      int r = s >> 3, p = s & 7;
      gload16(&Sb[k1][((size_t)b * 512 + n0 + r) * 64 + 8 * (p ^ (r & 7))],
              &Sl[k1][(it * 256 + w * 64) * 8]);
    }
  s16x8 aw[7][2];
  {
    const u16* w0 = WTp + (size_t)colr * 224 + g * 8;
    const u16* w1 = WTp + (size_t)(colr + 64) * 224 + g * 8;
    #pragma unroll
    for (int kt = 0; kt < 7; ++kt) {
      aw[kt][0] = *(const s16x8*)&w0[kt * 32];
      aw[kt][1] = *(const s16x8*)&w1[kt * 32];
    }
  }
  for (int i = tid; i < 64 * 36; i += 256)
    if ((i % 36) >= 6) St[i] = 0;
  for (int t = tid; t < 384; t += 256) {
    int k1 = t >> 7, rr = (t >> 1) & 63, c = t & 1;
    u16 v;
    if (k1 == 0) v = f2bf(inp[((size_t)b * 512 + n0 + rr) * 2 + c]);
    else {
      const u16* Yk = (k1 == 1) ? Yi1 : Yi2;
      v = Yk[((size_t)b * 2 + c) * 512 + (n0 + rr)];
    }
    St[rr * 36 + k1 * 2 + c] = v;
  }
  asm volatile("s_waitcnt vmcnt(0)" ::: "memory");
  __syncthreads();

  f32x4 acc0[4] = {}, acc1[4] = {};
  #pragma unroll
  for (int kt = 0; kt < 7; ++kt) {
    #pragma unroll
    for (int ns = 0; ns < 4; ++ns) {
      int rn = ns * 16 + l16;
      s16x4 lo, hi;
      if (kt < 6) {
        const int buf = kt >> 1, ft = kt & 1;
        int c0 = ft * 4 + (g >> 1), c1 = c0 + 2;
        const char* rowp = (const char*)Sl[buf] + rn * 128 + 8 * (g & 1);
        lo = *(const s16x4*)(rowp + 16 * (c0 ^ (rn & 7)));
        hi = *(const s16x4*)(rowp + 16 * (c1 ^ (rn & 7)));
      } else {
        const char* rowp = (const char*)St + rn * 72 + 8 * g;
        lo = *(const s16x4*)(rowp);
        hi = *(const s16x4*)(rowp + 32);
      }
      s16x8 bs = __builtin_shufflevector(lo, hi, 0, 1, 2, 3, 4, 5, 6, 7);
      acc0[ns] = __builtin_amdgcn_mfma_f32_16x16x32_bf16(aw[kt][0], bs, acc0[ns], 0, 0, 0);
      acc1[ns] = __builtin_amdgcn_mfma_f32_16x16x32_bf16(aw[kt][1], bs, acc1[ns], 0, 0, 0);
    }
  }
  __syncthreads();   // all waves done reading Sl[1] before bounce reuse

  f32x4 b4r = *(const f32x4*)&bias[w * 16 + 4 * g];
  f32x4 b4u = *(const f32x4*)&bias[64 + w * 16 + 4 * g];
  const int chk = 2 * w + (g >> 1);
  #pragma unroll
  for (int ns = 0; ns < 4; ++ns) {
    int rn = ns * 16 + l16;
    int n = n0 + rn;
    size_t base = ((size_t)b * 512 + n) * 64 + w * 16 + 4 * g;
    const char* srow = (const char*)Sl[0] + rn * 128 + 8 * (g & 1);
    s16x4 st4 = *(const s16x4*)(srow + 16 * (chk ^ (rn & 7)));
    s16x4 o;
    #pragma unroll
    for (int r = 0; r < 4; ++r) {
      float x = acc0[ns][r] + b4r[r];
      float sg = 1.0f / (1.0f + expf(-x));
      o[r] = (short)f2bf(sg * bf2f((u16)st4[r]));
    }
    *(s16x4*)&XC0n[base] = o;
    #pragma unroll
    for (int r = 0; r < 4; ++r)
      Sl[1][(w * 16 + 4 * g + r) * 64 + rn] = (u16)o[r];   // bounce tile [64f][64n]
    s16x4 uo;
    #pragma unroll
    for (int r = 0; r < 4; ++r) {
      float x = acc1[ns][r] + b4u[r];
      uo[r] = (short)f2bf(1.0f / (1.0f + expf(-x)));
    }
    *(s16x4*)&Ub[base] = uo;
  }
  __syncthreads();
  #pragma unroll
  for (int i = 0; i < 2; ++i) {
    int s = i * 256 + tid, f = s >> 3, c = s & 7;
    *(s16x8*)&XC0t[(size_t)(b * 64 + f) * 512 + n0 + c * 8] =
        *(const s16x8*)&Sl[1][f * 64 + c * 8];
  }
}

// ---------------- candidate applyW: NC=64, out = u*state + (1-u)*tanh ----------------
__global__ __launch_bounds__(256) void k_applyC(
    const u16* __restrict__ S0b, const u16* __restrict__ S1b, const u16* __restrict__ S2b,
    const float* __restrict__ inp, const u16* __restrict__ Yi1, const u16* __restrict__ Yi2,
    const u16* __restrict__ WTp, const float* __restrict__ bias,
    const float* __restrict__ state, const u16* __restrict__ Ub, float* __restrict__ outp) {
  __shared__ __align__(16) u16 Sl[3][4096];
  __shared__ __align__(16) u16 St[64 * 36];
  const int tid = threadIdx.x;
  const int w = tid >> 6, l = tid & 63, g = l >> 4, l16 = l & 15;
  const int b = blockIdx.y, n0 = blockIdx.x * 64;
  const int colr = w * 16 + l16;

  const u16* Sb[3] = {S0b, S1b, S2b};
  #pragma unroll
  for (int k1 = 0; k1 < 3; ++k1)
    #pragma unroll
    for (int it = 0; it < 2; ++it) {
      int s = it * 256 + tid;
      int r = s >> 3, p = s & 7;
      gload16(&Sb[k1][((size_t)b * 512 + n0 + r) * 64 + 8 * (p ^ (r & 7))],
              &Sl[k1][(it * 256 + w * 64) * 8]);
    }
  s16x8 aw[7];
  {
    const u16* w0 = WTp + (size_t)colr * 224 + g * 8;
    #pragma unroll
    for (int kt = 0; kt < 7; ++kt) aw[kt] = *(const s16x8*)&w0[kt * 32];
  }
  for (int i = tid; i < 64 * 36; i += 256)
    if ((i % 36) >= 6) St[i] = 0;
  for (int t = tid; t < 384; t += 256) {
    int k1 = t >> 7, rr = (t >> 1) & 63, c = t & 1;
    u16 v;
    if (k1 == 0) v = f2bf(inp[((size_t)b * 512 + n0 + rr) * 2 + c]);
    else {
      const u16* Yk = (k1 == 1) ? Yi1 : Yi2;
      v = Yk[((size_t)b * 2 + c) * 512 + (n0 + rr)];
    }
    St[rr * 36 + k1 * 2 + c] = v;
  }
  asm volatile("s_waitcnt vmcnt(0)" ::: "memory");
  __syncthreads();

  f32x4 acc[4] = {};
  #pragma unroll
  for (int kt = 0; kt < 7; ++kt) {
    #pragma unroll
    for (int ns = 0; ns < 4; ++ns) {
      int rn = ns * 16 + l16;
      s16x4 lo, hi;
      if (kt < 6) {
        const int buf = kt >> 1, ft = kt & 1;
        int c0 = ft * 4 + (g >> 1), c1 = c0 + 2;
        const char* rowp = (const char*)Sl[buf] + rn * 128 + 8 * (g & 1);
        lo = *(const s16x4*)(rowp + 16 * (c0 ^ (rn & 7)));
        hi = *(const s16x4*)(rowp + 16 * (c1 ^ (rn & 7)));
      } else {
        const char* rowp = (const char*)St + rn * 72 + 8 * g;
        lo = *(const s16x4*)(rowp);
        hi = *(const s16x4*)(rowp + 32);
      }
      s16x8 bs = __builtin_shufflevector(lo, hi, 0, 1, 2, 3, 4, 5, 6, 7);
      acc[ns] = __builtin_amdgcn_mfma_f32_16x16x32_bf16(aw[kt], bs, acc[ns], 0, 0, 0);
    }
  }

  f32x4 b4 = *(const f32x4*)&bias[w * 16 + 4 * g];
  #pragma unroll
  for (int ns = 0; ns < 4; ++ns) {
    int n = n0 + ns * 16 + l16;
    size_t base = ((size_t)b * 512 + n) * 64 + w * 16 + 4 * g;
    s16x4 ub4 = *(const s16x4*)&Ub[base];
    f32x4 st4 = *(const f32x4*)&state[base];
    f32x4 o;
    #pragma unroll
    for (int r = 0; r < 4; ++r) {
      float c = tanhf(acc[ns][r] + b4[r]);
      float u = bf2f((u16)ub4[r]);
      o[r] = fmaf(u, st4[r] - c, c);
    }
    *(f32x4*)&outp[base] = o;
  }
}

extern "C" void kernel_launch(void* const* d_in, const int* in_sizes, int n_in,
                              void* d_out, int out_size, void* d_ws, size_t ws_size,
                              hipStream_t stream) {
  const float* inp   = (const float*)d_in[0];
  const float* state = (const float*)d_in[1];
  const float* adj   = (const float*)d_in[2];
  const float* Wg    = (const float*)d_in[3];
  const float* bg    = (const float*)d_in[4];
  const float* Wc    = (const float*)d_in[5];
  const float* bc    = (const float*)d_in[6];
  float* out = (float*)d_out;

  char* p = (char*)d_ws;
  u16* Abf    = (u16*)p; p += 524288;      // Ab[n][m]
  u16* XAll0t = (u16*)p; p += 17301504;    // [16896][512]: XG0t (later XC0t) + Xi0t tail
  u16* X1t    = (u16*)p; p += 17301504;    // [16896][512]: X1t batch + Yi1t tail
  u16* Yi2t   = (u16*)p; p += 524288;      // [512][512]
  u16* WTpg   = (u16*)p; p += 57344;       // [128][224] permuted
  u16* WTpc   = (u16*)p; p += 28672;       // [64][224]
  float* dinv = (float*)p; p += 2048;
  u16* XG0n   = (u16*)p; p += 16777216;    // [b][n][64]; reused as Ub after applyG stages it
  u16* XC0n   = (u16*)p; p += 16777216;
  u16* X1n    = (u16*)p; p += 16777216;
  u16* X2n    = (u16*)p; p += 16777216;    // total ~98.1 MB
  u16* Xi0t   = XAll0t + (size_t)16384 * 512;
  u16* XC0t   = XAll0t;                    // alias: XG0t dead after gate hop 2
  u16* Yi1t   = X1t + (size_t)16384 * 512;
  u16* Yi2off = Yi2t - (size_t)16384 * 512;  // Yt base for hop2 (only R>=16384 deref'd)
  u16* Ub     = XG0n;                      // alias: same-block footprint, staged before written

  k_dinv   <<<512, 64,  0, stream>>>(adj, dinv);
  k_buildA <<<512, 256, 0, stream>>>(adj, dinv, Abf);
  k_prepST <<<dim3(8, 256), 256, 0, stream>>>(state, XG0n, XAll0t);
  k_prepI  <<<256, 256, 0, stream>>>(inp, Xi0t);
  k_wtp<128><<<128, 256, 0, stream>>>(Wg, WTpg);
  k_wtp<64> <<<64, 256, 0, stream>>>(Wc, WTpc);

  // gate path (input rows folded in: y covers 16384 batch + 512 input rows)
  k_diffB<0, 1, 1><<<dim3(4, 132), 256, 0, stream>>>(XAll0t, Abf, nullptr, X1t, X1n);
  k_diffB<1, 0, 1><<<dim3(4, 132), 256, 0, stream>>>(X1t, Abf, XAll0t, Yi2off, X2n);
  k_applyG<<<dim3(8, 256), 256, 0, stream>>>(XG0n, X1n, X2n, inp, Yi1t, Yi2t,
                                             WTpg, bg, XC0n, XC0t, Ub);

  // candidate path (batch rows only; input diffusion reused)
  k_diffB<0, 1, 1><<<dim3(4, 128), 256, 0, stream>>>(XC0t, Abf, nullptr, X1t, X1n);
  k_diffB<1, 0, 1><<<dim3(4, 128), 256, 0, stream>>>(X1t, Abf, XC0t, Yi2off, X2n);
  k_applyC<<<dim3(8, 256), 256, 0, stream>>>(XC0n, X1n, X2n, inp, Yi1t, Yi2t,
                                             WTpc, bc, state, Ub, out);
}